// Round 8
// baseline (654.579 us; speedup 1.0000x reference)
//
#include <hip/hip_runtime.h>
#include <stdint.h>

// DenseGGNN on MI355X, round 8.
//  - k_mega5 = round-7 k_mega4 with 32-row tiles: grid 1024 (4 blocks/CU, 16 waves/CU
//    vs 8), single-buffered 36 KB LDS phase 1 (m97-style 2-barrier; cross-block
//    overlap masks the drain at 4 blocks/CU). XOR bank swizzle kept (0 conflicts).
//    Phase-2 h-chunks before the m barrier kept. Numerics path unchanged.
//  - k_setup / k_hw unchanged.

#define NB 32
#define NN 1024
#define NC 128
#define NL 4
#define MTOT (NB * NN)   // 32768

#define KT 64
#define PITCH 72         // k_hw LDS pitch

typedef __attribute__((ext_vector_type(8))) short s16x8;
typedef __attribute__((ext_vector_type(4))) float f32x4;
typedef __attribute__((ext_vector_type(2))) unsigned int u32x2;
typedef unsigned short U16;
typedef unsigned int U32;

__device__ __forceinline__ U16 f2bf(float f) {
    union { float f; U32 u; } v; v.f = f;
    return (U16)((v.u + 0x7FFFu + ((v.u >> 16) & 1u)) >> 16);  // RNE
}
__device__ __forceinline__ float bf2f(U16 h) {
    union { U32 u; float f; } v; v.u = ((U32)h) << 16;
    return v.f;
}
__device__ __forceinline__ void splitbf(float x, U16& hi, U16& lo) {
    hi = f2bf(x);
    lo = f2bf(x - bf2f(hi));
}
__device__ __forceinline__ float sigmoidf_(float x) { return 1.f / (1.f + __expf(-x)); }

__device__ __forceinline__ void glds16(const void* g, void* l) {
    __builtin_amdgcn_global_load_lds(
        (const __attribute__((address_space(1))) void*)g,
        (__attribute__((address_space(3))) void*)l, 16, 0, 0);
}

// swizzled LDS offset: row stride 64 U16, k-group g XORed with row&7
#define SWZ(row, g) ((row) * 64 + ((((g) ^ ((row) & 7))) * 8))

// ---------------- setup: adjT transpose + weight split + h init ----------------
__global__ __launch_bounds__(256) void k_setup(
    const float* __restrict__ adj, U16* __restrict__ adjT,
    const float* __restrict__ w, const float* __restrict__ wih, const float* __restrict__ whh,
    U16* __restrict__ wThi, U16* __restrict__ wTlo,
    U16* __restrict__ wihhi, U16* __restrict__ wihlo,
    U16* __restrict__ whhhi, U16* __restrict__ whhlo,
    const float* __restrict__ x, U16* __restrict__ hhi, U16* __restrict__ hlo)
{
    __shared__ float t[64 * 65];
    const int bid = blockIdx.x, tid = threadIdx.x;
    if (bid < 8192) {                              // adj fp32 [b][j][n] -> adjT bf16 [b][n][j]
        const int b = bid >> 8, rem = bid & 255;
        const int j0 = (rem & 15) * 64, n0 = (rem >> 4) * 64;
        const int rr = tid >> 4, c4 = (tid & 15) * 4;
#pragma unroll
        for (int p = 0; p < 4; ++p) {
            int j = p * 16 + rr;
            f32x4 v = *(const f32x4*)&adj[((size_t)b << 20) + ((size_t)(j0 + j) << 10) + n0 + c4];
#pragma unroll
            for (int u = 0; u < 4; ++u) t[j * 65 + c4 + u] = v[u];
        }
        __syncthreads();
#pragma unroll
        for (int p = 0; p < 4; ++p) {
            int n = p * 16 + rr;
            U16 h0 = f2bf(t[(c4 + 0) * 65 + n]);
            U16 h1 = f2bf(t[(c4 + 1) * 65 + n]);
            U16 h2 = f2bf(t[(c4 + 2) * 65 + n]);
            U16 h3 = f2bf(t[(c4 + 3) * 65 + n]);
            u32x2 pk; pk[0] = (U32)h0 | ((U32)h1 << 16); pk[1] = (U32)h2 | ((U32)h3 << 16);
            *(u32x2*)&adjT[((size_t)b << 20) + ((size_t)(n0 + n) << 10) + j0 + c4] = pk;
        }
    } else if (bid < 9984) {                       // weight split (458752 elements)
        int i = (bid - 8192) * 256 + tid;
        if (i < 65536) {                           // weight [L][C][C] -> wT [L][d][c]
            int l = i >> 14, rem = i & 16383, c = rem >> 7, d = rem & 127;
            U16 hi, lo; splitbf(w[i], hi, lo);
            int o = (l << 14) + (d << 7) + c;
            wThi[o] = hi; wTlo[o] = lo;
        } else if (i < 262144) {
            int j = i - 65536;
            U16 hi, lo; splitbf(wih[j], hi, lo);
            wihhi[j] = hi; wihlo[j] = lo;
        } else {
            int j = i - 262144;
            U16 hi, lo; splitbf(whh[j], hi, lo);
            whhhi[j] = hi; whhlo[j] = lo;
        }
    } else {                                       // h init from x (4.19M elements)
        int base = (bid - 9984) * 2048 + tid;
#pragma unroll
        for (int p = 0; p < 8; ++p) {
            int i = base + p * 256;
            U16 hi, lo; splitbf(x[i], hi, lo);
            hhi[i] = hi; hlo[i] = lo;
        }
    }
}

// ---------------- K1: hw = h @ W (3-product), writes hwT[b][d][j] hi/lo ----------------
struct __align__(16) Smem3 {
    union {
        struct { U16 A[2][128 * PITCH]; U16 B[2][128 * PITCH]; } s;   // 73728 B
        float bounce[128 * 129];                                      // 66048 B
    };
};

__global__ __launch_bounds__(256, 2) void k_hw(
    const U16* __restrict__ Ahi, const U16* __restrict__ Alo,
    const U16* __restrict__ Bhi, const U16* __restrict__ Blo,
    U16* __restrict__ Ohi, U16* __restrict__ Olo)
{
    __shared__ Smem3 sm;
    const int tid = threadIdx.x;
    const int lane = tid & 63, wv = tid >> 6;
    const int wr = (wv & 1) * 64, wc = (wv >> 1) * 64;
    const int lm = lane & 15, lk8 = (lane >> 4) * 8;
    const int m0 = blockIdx.x * 128;

    f32x4 acc[4][4] = {};

    for (int kc = 0; kc < 128; kc += KT) {
#pragma unroll
        for (int t = 0; t < 4; ++t) {
            int i = tid + t * 256; int r = i >> 3, v = (i & 7) * 8;
            *(s16x8*)&sm.s.A[0][r * PITCH + v] = *(const s16x8*)&Ahi[(size_t)(m0 + r) * 128 + kc + v];
            *(s16x8*)&sm.s.A[1][r * PITCH + v] = *(const s16x8*)&Alo[(size_t)(m0 + r) * 128 + kc + v];
        }
#pragma unroll
        for (int t = 0; t < 4; ++t) {
            int i = tid + t * 256; int r = i >> 3, v = (i & 7) * 8;
            *(s16x8*)&sm.s.B[0][r * PITCH + v] = *(const s16x8*)&Bhi[r * 128 + kc + v];
            *(s16x8*)&sm.s.B[1][r * PITCH + v] = *(const s16x8*)&Blo[r * 128 + kc + v];
        }
        __syncthreads();
#pragma unroll
        for (int ks = 0; ks < 2; ++ks) {
            const int ko = ks * 32 + lk8;
            s16x8 ahi[4], alo[4], bhi[4], blo[4];
#pragma unroll
            for (int q = 0; q < 4; ++q) {
                ahi[q] = *(const s16x8*)&sm.s.A[0][(wr + q * 16 + lm) * PITCH + ko];
                alo[q] = *(const s16x8*)&sm.s.A[1][(wr + q * 16 + lm) * PITCH + ko];
                bhi[q] = *(const s16x8*)&sm.s.B[0][(wc + q * 16 + lm) * PITCH + ko];
                blo[q] = *(const s16x8*)&sm.s.B[1][(wc + q * 16 + lm) * PITCH + ko];
            }
#pragma unroll
            for (int rt = 0; rt < 4; ++rt)
#pragma unroll
                for (int ct = 0; ct < 4; ++ct) {
                    f32x4 a = acc[rt][ct];
                    a = __builtin_amdgcn_mfma_f32_16x16x32_bf16(ahi[rt], bhi[ct], a, 0, 0, 0);
                    a = __builtin_amdgcn_mfma_f32_16x16x32_bf16(ahi[rt], blo[ct], a, 0, 0, 0);
                    a = __builtin_amdgcn_mfma_f32_16x16x32_bf16(alo[rt], bhi[ct], a, 0, 0, 0);
                    acc[rt][ct] = a;
                }
        }
        __syncthreads();
    }
#pragma unroll
    for (int rt = 0; rt < 4; ++rt)
#pragma unroll
        for (int ct = 0; ct < 4; ++ct)
#pragma unroll
            for (int r = 0; r < 4; ++r)
                sm.bounce[(wr + rt * 16 + (lane >> 4) * 4 + r) * 129 + wc + ct * 16 + lm] = acc[rt][ct][r];
    __syncthreads();
    const int b = m0 >> 10, j0 = m0 & 1023;
    for (int t = 0; t < 32; ++t) {
        int i = tid + t * 256; int d = i >> 6, j2 = (i & 63) * 2;
        float x0 = sm.bounce[j2 * 129 + d], x1 = sm.bounce[(j2 + 1) * 129 + d];
        U16 h0, l0, h1, l1; splitbf(x0, h0, l0); splitbf(x1, h1, l1);
        size_t o = (((size_t)(b * 128 + d)) << 10) + j0 + j2;
        *(U32*)&Ohi[o] = (U32)h0 | ((U32)h1 << 16);
        *(U32*)&Olo[o] = (U32)l0 | ((U32)l1 << 16);
    }
}

// ---------------- k_mega5: 32-row tiles, 4 blocks/CU; adjT-GEMM -> m -> gates -> GRU ----------------
__global__ __launch_bounds__(256, 4) void k_mega5(
    const U16* __restrict__ adjT,                                 // [NB][NN][NN]
    const U16* __restrict__ hwThi, const U16* __restrict__ hwTlo, // [NB][128][1024]
    U16* mhi, U16* mlo,                                           // [MTOT][128] scratch (W->R)
    const U16* __restrict__ hhi, const U16* __restrict__ hlo,     // [MTOT][128]
    const U16* __restrict__ wihhi, const U16* __restrict__ wihlo, // [384][128] layer slice
    const U16* __restrict__ whhhi, const U16* __restrict__ whhlo,
    const float* __restrict__ bih, const float* __restrict__ bhh, // [384] layer slice
    const float* __restrict__ mask,
    U16* __restrict__ houthi, U16* __restrict__ houtlo,
    float* __restrict__ out, int last)
{
    __shared__ U16 As[32 * 64];    // 4 KB (glds: unpadded + XOR swizzle)
    __shared__ U16 Bh[128 * 64];   // 16 KB
    __shared__ U16 Bl[128 * 64];   // 16 KB -> 36 KB total, 4 blocks/CU
    const int tid = threadIdx.x;
    const int lane = tid & 63, wv = tid >> 6;
    const int wd0 = wv * 32;                       // wave's 32-col slice
    const int lm = lane & 15, lk8 = (lane >> 4) * 8, quad = lane >> 4;
    const int xcd = blockIdx.x & 7;
    const int j = blockIdx.x >> 3;                 // 0..127
    const int bt = xcd * 4 + (j >> 5);
    const int n0 = (j & 31) * 32;
    const int row0 = bt * NN + n0;

    // ---- phase 1: m = adjT @ hw (2-product), single-buffer 2-barrier, swizzled ----
#define STAGE(kc)                                                                        \
    {                                                                                    \
        {                                                                                \
            int r = tid >> 3, sg = tid & 7;                                              \
            glds16(&adjT[((size_t)bt << 20) + ((size_t)(n0 + r) << 10) + (kc)            \
                         + ((sg ^ (r & 7)) * 8)],                                        \
                   &As[tid * 8]);                                                        \
        }                                                                                \
        _Pragma("unroll")                                                                \
        for (int t = 0; t < 4; ++t) {                                                    \
            int li = tid + t * 256; int d = li >> 3, sg = li & 7;                        \
            size_t o = (((size_t)(bt * 128 + d)) << 10) + (kc) + ((sg ^ (d & 7)) * 8);   \
            glds16(&hwThi[o], &Bh[li * 8]);                                              \
            glds16(&hwTlo[o], &Bl[li * 8]);                                              \
        }                                                                                \
    }

    f32x4 macc[2][2] = {};
    for (int c = 0; c < 16; ++c) {
        STAGE(c * 64);
        __syncthreads();                           // glds drained, buffer ready
#pragma unroll
        for (int ks = 0; ks < 2; ++ks) {
            const int g = ks * 4 + quad;           // k-group 0..7
            s16x8 a[2], bh[2], bl[2];
#pragma unroll
            for (int q = 0; q < 2; ++q)
                a[q] = *(const s16x8*)&As[SWZ(q * 16 + lm, g)];
#pragma unroll
            for (int q = 0; q < 2; ++q) {
                bh[q] = *(const s16x8*)&Bh[SWZ(wd0 + q * 16 + lm, g)];
                bl[q] = *(const s16x8*)&Bl[SWZ(wd0 + q * 16 + lm, g)];
            }
#pragma unroll
            for (int rt = 0; rt < 2; ++rt)
#pragma unroll
                for (int ct = 0; ct < 2; ++ct) {
                    f32x4 cc = macc[rt][ct];
                    cc = __builtin_amdgcn_mfma_f32_16x16x32_bf16(a[rt], bh[ct], cc, 0, 0, 0);
                    cc = __builtin_amdgcn_mfma_f32_16x16x32_bf16(a[rt], bl[ct], cc, 0, 0, 0);
                    macc[rt][ct] = cc;
                }
        }
        __syncthreads();                           // compute done before restage
    }
#undef STAGE

    // ---- m -> global hi/lo (block owns complete rows) ----
#pragma unroll
    for (int rt = 0; rt < 2; ++rt)
#pragma unroll
        for (int ct = 0; ct < 2; ++ct)
#pragma unroll
            for (int rr = 0; rr < 4; ++rr) {
                int rloc = rt * 16 + quad * 4 + rr;
                int d = wd0 + ct * 16 + lm;
                U16 hi, lo; splitbf(macc[rt][ct][rr], hi, lo);
                size_t o = (size_t)(row0 + rloc) * 128 + d;
                mhi[o] = hi; mlo[o] = lo;
            }
    // no barrier yet — h-chunks first, barrier before m-chunks

    // ---- phase 2: gates (K=256 concat [m|h], 3-product) + GRU ----
    f32x4 aR[2][2], aZ[2][2], aXN[2][2], aHN[2][2];
#pragma unroll
    for (int ct = 0; ct < 2; ++ct) {
        const int col = wd0 + ct * 16 + lm;
        const float bR  = bih[col]       + bhh[col];
        const float bZ  = bih[128 + col] + bhh[128 + col];
        const float bXN = bih[256 + col];
        const float bHN = bhh[256 + col];
#pragma unroll
        for (int rt = 0; rt < 2; ++rt) {
            aR[rt][ct]  = f32x4{bR, bR, bR, bR};
            aZ[rt][ct]  = f32x4{bZ, bZ, bZ, bZ};
            aXN[rt][ct] = f32x4{bXN, bXN, bXN, bXN};
            aHN[rt][ct] = f32x4{bHN, bHN, bHN, bHN};
        }
    }

    for (int cc = 0; cc < 4; ++cc) {
        const int ch = (cc + 2) & 3;               // order: 2,3 (h) then 0,1 (m)
        if (cc == 2) __syncthreads();              // m-stores drained + visible block-wide
        const U16* Ahi = (ch < 2) ? (const U16*)mhi : hhi;
        const U16* Alo = (ch < 2) ? (const U16*)mlo : hlo;
        const U16* __restrict__ Whi = (ch < 2) ? wihhi : whhhi;
        const U16* __restrict__ Wlo = (ch < 2) ? wihlo : whhlo;
        const int kb = (ch & 1) * 64;
#pragma unroll
        for (int ks = 0; ks < 2; ++ks) {
            const int ko = kb + ks * 32 + lk8;     // k within [0,128)
            s16x8 ahi[2], alo[2];
#pragma unroll
            for (int q = 0; q < 2; ++q) {
                size_t ao = (size_t)(row0 + q * 16 + lm) * 128 + ko;
                ahi[q] = *(const s16x8*)&Ahi[ao];
                alo[q] = *(const s16x8*)&Alo[ao];
            }
#pragma unroll
            for (int ct = 0; ct < 2; ++ct) {
                const int col = wd0 + ct * 16 + lm;
                s16x8 bhiR = *(const s16x8*)&Whi[(size_t)col * 128 + ko];
                s16x8 bloR = *(const s16x8*)&Wlo[(size_t)col * 128 + ko];
                s16x8 bhiZ = *(const s16x8*)&Whi[(size_t)(128 + col) * 128 + ko];
                s16x8 bloZ = *(const s16x8*)&Wlo[(size_t)(128 + col) * 128 + ko];
                s16x8 bhiN = *(const s16x8*)&Whi[(size_t)(256 + col) * 128 + ko];
                s16x8 bloN = *(const s16x8*)&Wlo[(size_t)(256 + col) * 128 + ko];
#pragma unroll
                for (int rt = 0; rt < 2; ++rt) {
                    f32x4 r = aR[rt][ct];
                    r = __builtin_amdgcn_mfma_f32_16x16x32_bf16(ahi[rt], bhiR, r, 0, 0, 0);
                    r = __builtin_amdgcn_mfma_f32_16x16x32_bf16(ahi[rt], bloR, r, 0, 0, 0);
                    r = __builtin_amdgcn_mfma_f32_16x16x32_bf16(alo[rt], bhiR, r, 0, 0, 0);
                    aR[rt][ct] = r;
                    f32x4 z = aZ[rt][ct];
                    z = __builtin_amdgcn_mfma_f32_16x16x32_bf16(ahi[rt], bhiZ, z, 0, 0, 0);
                    z = __builtin_amdgcn_mfma_f32_16x16x32_bf16(ahi[rt], bloZ, z, 0, 0, 0);
                    z = __builtin_amdgcn_mfma_f32_16x16x32_bf16(alo[rt], bhiZ, z, 0, 0, 0);
                    aZ[rt][ct] = z;
                }
                if (ch < 2) {
#pragma unroll
                    for (int rt = 0; rt < 2; ++rt) {
                        f32x4 n = aXN[rt][ct];
                        n = __builtin_amdgcn_mfma_f32_16x16x32_bf16(ahi[rt], bhiN, n, 0, 0, 0);
                        n = __builtin_amdgcn_mfma_f32_16x16x32_bf16(ahi[rt], bloN, n, 0, 0, 0);
                        n = __builtin_amdgcn_mfma_f32_16x16x32_bf16(alo[rt], bhiN, n, 0, 0, 0);
                        aXN[rt][ct] = n;
                    }
                } else {
#pragma unroll
                    for (int rt = 0; rt < 2; ++rt) {
                        f32x4 n = aHN[rt][ct];
                        n = __builtin_amdgcn_mfma_f32_16x16x32_bf16(ahi[rt], bhiN, n, 0, 0, 0);
                        n = __builtin_amdgcn_mfma_f32_16x16x32_bf16(ahi[rt], bloN, n, 0, 0, 0);
                        n = __builtin_amdgcn_mfma_f32_16x16x32_bf16(alo[rt], bhiN, n, 0, 0, 0);
                        aHN[rt][ct] = n;
                    }
                }
            }
        }
    }

    // ---- GRU epilogue; h re-read from global; in-place h update ----
#pragma unroll
    for (int rt = 0; rt < 2; ++rt) {
#pragma unroll
        for (int ct = 0; ct < 2; ++ct) {
            const int col = wd0 + ct * 16 + lm;
#pragma unroll
            for (int rr = 0; rr < 4; ++rr) {
                const int row = row0 + rt * 16 + quad * 4 + rr;
                float r = sigmoidf_(aR[rt][ct][rr]);
                float z = sigmoidf_(aZ[rt][ct][rr]);
                float n = tanhf(aXN[rt][ct][rr] + r * aHN[rt][ct][rr]);
                size_t ho = (size_t)row * 128 + col;
                float hv = bf2f(hhi[ho]) + bf2f(hlo[ho]);
                float hnew = (1.f - z) * n + z * hv;
                if (last) {
                    out[ho] = hnew * mask[row];
                } else {
                    U16 hi2, lo2; splitbf(hnew, hi2, lo2);
                    houthi[ho] = hi2;
                    houtlo[ho] = lo2;
                }
            }
        }
    }
}

// ---------------- launch ----------------
extern "C" void kernel_launch(void* const* d_in, const int* in_sizes, int n_in,
                              void* d_out, int out_size, void* d_ws, size_t ws_size,
                              hipStream_t stream) {
    (void)in_sizes; (void)n_in; (void)out_size; (void)ws_size;
    const float* x    = (const float*)d_in[0];
    const float* adj  = (const float*)d_in[1];
    const float* mask = (const float*)d_in[2];
    const float* wgt  = (const float*)d_in[3];
    const float* wih  = (const float*)d_in[4];
    const float* whh  = (const float*)d_in[5];
    const float* bih  = (const float*)d_in[6];
    const float* bhh  = (const float*)d_in[7];
    float* out = (float*)d_out;

    char* p = (char*)d_ws;
    U16* adjT    = (U16*)p;                p += (size_t)NB * NN * NN * 2;   // 67.1 MB
    U16* h_hi    = (U16*)p;                p += (size_t)MTOT * NC * 2;
    U16* h_lo    = (U16*)p;                p += (size_t)MTOT * NC * 2;
    U16* hwT_hi  = (U16*)p;                p += (size_t)NB * NC * NN * 2;
    U16* hwT_lo  = (U16*)p;                p += (size_t)NB * NC * NN * 2;
    U16* m_hi    = (U16*)p;                p += (size_t)MTOT * NC * 2;
    U16* m_lo    = (U16*)p;                p += (size_t)MTOT * NC * 2;
    U16* wT_hi   = (U16*)p;                p += (size_t)NL * NC * NC * 2;
    U16* wT_lo   = (U16*)p;                p += (size_t)NL * NC * NC * 2;
    U16* wih_hi  = (U16*)p;                p += (size_t)NL * 384 * NC * 2;
    U16* wih_lo  = (U16*)p;                p += (size_t)NL * 384 * NC * 2;
    U16* whh_hi  = (U16*)p;                p += (size_t)NL * 384 * NC * 2;
    U16* whh_lo  = (U16*)p;                p += (size_t)NL * 384 * NC * 2;

    k_setup<<<12032, 256, 0, stream>>>(adj, adjT, wgt, wih, whh,
                                       wT_hi, wT_lo, wih_hi, wih_lo, whh_hi, whh_lo,
                                       x, h_hi, h_lo);

    for (int l = 0; l < NL; ++l) {
        k_hw<<<256, 256, 0, stream>>>(h_hi, h_lo,
                                      wT_hi + l * 16384, wT_lo + l * 16384,
                                      hwT_hi, hwT_lo);
        k_mega5<<<1024, 256, 0, stream>>>(adjT, hwT_hi, hwT_lo, m_hi, m_lo, h_hi, h_lo,
                                          wih_hi + l * 49152, wih_lo + l * 49152,
                                          whh_hi + l * 49152, whh_lo + l * 49152,
                                          bih + l * 384, bhh + l * 384, mask,
                                          h_hi, h_lo, out, (l == NL - 1) ? 1 : 0);
    }
}

// Round 9
// 514.924 us; speedup vs baseline: 1.2712x; 1.2712x over previous
//
#include <hip/hip_runtime.h>
#include <stdint.h>

// DenseGGNN on MI355X, round 9.
//  - k_mega6 = round-7 k_mega4 (best measured: 64-row tiles, dbuf glds pipeline,
//    XOR bank swizzle, XCD batch swizzle) + m kept in LDS (union with staging
//    buffers) instead of the global round-trip. R4's m-in-LDS failure was an
//    h-staging index bug (li>>3 vs li>>4), not the m-bounce; h stays global here.
//  - Order: phase1 -> barrier -> m ds_writes -> h-chunks (global) -> barrier ->
//    m-chunks (LDS) -> GRU. Numerics path bit-identical to rounds 5-8.
//  - k_setup / k_hw unchanged.

#define NB 32
#define NN 1024
#define NC 128
#define NL 4
#define MTOT (NB * NN)   // 32768

#define KT 64
#define PITCH 72         // k_hw LDS pitch
#define MP 136           // m-LDS pitch (U16): row stride 272B -> bank step 4, <=2-way reads

typedef __attribute__((ext_vector_type(8))) short s16x8;
typedef __attribute__((ext_vector_type(4))) float f32x4;
typedef __attribute__((ext_vector_type(2))) unsigned int u32x2;
typedef unsigned short U16;
typedef unsigned int U32;

__device__ __forceinline__ U16 f2bf(float f) {
    union { float f; U32 u; } v; v.f = f;
    return (U16)((v.u + 0x7FFFu + ((v.u >> 16) & 1u)) >> 16);  // RNE
}
__device__ __forceinline__ float bf2f(U16 h) {
    union { U32 u; float f; } v; v.u = ((U32)h) << 16;
    return v.f;
}
__device__ __forceinline__ void splitbf(float x, U16& hi, U16& lo) {
    hi = f2bf(x);
    lo = f2bf(x - bf2f(hi));
}
__device__ __forceinline__ float sigmoidf_(float x) { return 1.f / (1.f + __expf(-x)); }

__device__ __forceinline__ void glds16(const void* g, void* l) {
    __builtin_amdgcn_global_load_lds(
        (const __attribute__((address_space(1))) void*)g,
        (__attribute__((address_space(3))) void*)l, 16, 0, 0);
}

// swizzled LDS offset: row stride 64 U16, k-group g XORed with row&7
#define SWZ(row, g) ((row) * 64 + ((((g) ^ ((row) & 7))) * 8))

// ---------------- setup: adjT transpose + weight split + h init ----------------
__global__ __launch_bounds__(256) void k_setup(
    const float* __restrict__ adj, U16* __restrict__ adjT,
    const float* __restrict__ w, const float* __restrict__ wih, const float* __restrict__ whh,
    U16* __restrict__ wThi, U16* __restrict__ wTlo,
    U16* __restrict__ wihhi, U16* __restrict__ wihlo,
    U16* __restrict__ whhhi, U16* __restrict__ whhlo,
    const float* __restrict__ x, U16* __restrict__ hhi, U16* __restrict__ hlo)
{
    __shared__ float t[64 * 65];
    const int bid = blockIdx.x, tid = threadIdx.x;
    if (bid < 8192) {                              // adj fp32 [b][j][n] -> adjT bf16 [b][n][j]
        const int b = bid >> 8, rem = bid & 255;
        const int j0 = (rem & 15) * 64, n0 = (rem >> 4) * 64;
        const int rr = tid >> 4, c4 = (tid & 15) * 4;
#pragma unroll
        for (int p = 0; p < 4; ++p) {
            int j = p * 16 + rr;
            f32x4 v = *(const f32x4*)&adj[((size_t)b << 20) + ((size_t)(j0 + j) << 10) + n0 + c4];
#pragma unroll
            for (int u = 0; u < 4; ++u) t[j * 65 + c4 + u] = v[u];
        }
        __syncthreads();
#pragma unroll
        for (int p = 0; p < 4; ++p) {
            int n = p * 16 + rr;
            U16 h0 = f2bf(t[(c4 + 0) * 65 + n]);
            U16 h1 = f2bf(t[(c4 + 1) * 65 + n]);
            U16 h2 = f2bf(t[(c4 + 2) * 65 + n]);
            U16 h3 = f2bf(t[(c4 + 3) * 65 + n]);
            u32x2 pk; pk[0] = (U32)h0 | ((U32)h1 << 16); pk[1] = (U32)h2 | ((U32)h3 << 16);
            *(u32x2*)&adjT[((size_t)b << 20) + ((size_t)(n0 + n) << 10) + j0 + c4] = pk;
        }
    } else if (bid < 9984) {                       // weight split (458752 elements)
        int i = (bid - 8192) * 256 + tid;
        if (i < 65536) {                           // weight [L][C][C] -> wT [L][d][c]
            int l = i >> 14, rem = i & 16383, c = rem >> 7, d = rem & 127;
            U16 hi, lo; splitbf(w[i], hi, lo);
            int o = (l << 14) + (d << 7) + c;
            wThi[o] = hi; wTlo[o] = lo;
        } else if (i < 262144) {
            int j = i - 65536;
            U16 hi, lo; splitbf(wih[j], hi, lo);
            wihhi[j] = hi; wihlo[j] = lo;
        } else {
            int j = i - 262144;
            U16 hi, lo; splitbf(whh[j], hi, lo);
            whhhi[j] = hi; whhlo[j] = lo;
        }
    } else {                                       // h init from x (4.19M elements)
        int base = (bid - 9984) * 2048 + tid;
#pragma unroll
        for (int p = 0; p < 8; ++p) {
            int i = base + p * 256;
            U16 hi, lo; splitbf(x[i], hi, lo);
            hhi[i] = hi; hlo[i] = lo;
        }
    }
}

// ---------------- K1: hw = h @ W (3-product), writes hwT[b][d][j] hi/lo ----------------
struct __align__(16) Smem3 {
    union {
        struct { U16 A[2][128 * PITCH]; U16 B[2][128 * PITCH]; } s;   // 73728 B
        float bounce[128 * 129];                                      // 66048 B
    };
};

__global__ __launch_bounds__(256, 2) void k_hw(
    const U16* __restrict__ Ahi, const U16* __restrict__ Alo,
    const U16* __restrict__ Bhi, const U16* __restrict__ Blo,
    U16* __restrict__ Ohi, U16* __restrict__ Olo)
{
    __shared__ Smem3 sm;
    const int tid = threadIdx.x;
    const int lane = tid & 63, wv = tid >> 6;
    const int wr = (wv & 1) * 64, wc = (wv >> 1) * 64;
    const int lm = lane & 15, lk8 = (lane >> 4) * 8;
    const int m0 = blockIdx.x * 128;

    f32x4 acc[4][4] = {};

    for (int kc = 0; kc < 128; kc += KT) {
#pragma unroll
        for (int t = 0; t < 4; ++t) {
            int i = tid + t * 256; int r = i >> 3, v = (i & 7) * 8;
            *(s16x8*)&sm.s.A[0][r * PITCH + v] = *(const s16x8*)&Ahi[(size_t)(m0 + r) * 128 + kc + v];
            *(s16x8*)&sm.s.A[1][r * PITCH + v] = *(const s16x8*)&Alo[(size_t)(m0 + r) * 128 + kc + v];
        }
#pragma unroll
        for (int t = 0; t < 4; ++t) {
            int i = tid + t * 256; int r = i >> 3, v = (i & 7) * 8;
            *(s16x8*)&sm.s.B[0][r * PITCH + v] = *(const s16x8*)&Bhi[r * 128 + kc + v];
            *(s16x8*)&sm.s.B[1][r * PITCH + v] = *(const s16x8*)&Blo[r * 128 + kc + v];
        }
        __syncthreads();
#pragma unroll
        for (int ks = 0; ks < 2; ++ks) {
            const int ko = ks * 32 + lk8;
            s16x8 ahi[4], alo[4], bhi[4], blo[4];
#pragma unroll
            for (int q = 0; q < 4; ++q) {
                ahi[q] = *(const s16x8*)&sm.s.A[0][(wr + q * 16 + lm) * PITCH + ko];
                alo[q] = *(const s16x8*)&sm.s.A[1][(wr + q * 16 + lm) * PITCH + ko];
                bhi[q] = *(const s16x8*)&sm.s.B[0][(wc + q * 16 + lm) * PITCH + ko];
                blo[q] = *(const s16x8*)&sm.s.B[1][(wc + q * 16 + lm) * PITCH + ko];
            }
#pragma unroll
            for (int rt = 0; rt < 4; ++rt)
#pragma unroll
                for (int ct = 0; ct < 4; ++ct) {
                    f32x4 a = acc[rt][ct];
                    a = __builtin_amdgcn_mfma_f32_16x16x32_bf16(ahi[rt], bhi[ct], a, 0, 0, 0);
                    a = __builtin_amdgcn_mfma_f32_16x16x32_bf16(ahi[rt], blo[ct], a, 0, 0, 0);
                    a = __builtin_amdgcn_mfma_f32_16x16x32_bf16(alo[rt], bhi[ct], a, 0, 0, 0);
                    acc[rt][ct] = a;
                }
        }
        __syncthreads();
    }
#pragma unroll
    for (int rt = 0; rt < 4; ++rt)
#pragma unroll
        for (int ct = 0; ct < 4; ++ct)
#pragma unroll
            for (int r = 0; r < 4; ++r)
                sm.bounce[(wr + rt * 16 + (lane >> 4) * 4 + r) * 129 + wc + ct * 16 + lm] = acc[rt][ct][r];
    __syncthreads();
    const int b = m0 >> 10, j0 = m0 & 1023;
    for (int t = 0; t < 32; ++t) {
        int i = tid + t * 256; int d = i >> 6, j2 = (i & 63) * 2;
        float x0 = sm.bounce[j2 * 129 + d], x1 = sm.bounce[(j2 + 1) * 129 + d];
        U16 h0, l0, h1, l1; splitbf(x0, h0, l0); splitbf(x1, h1, l1);
        size_t o = (((size_t)(b * 128 + d)) << 10) + j0 + j2;
        *(U32*)&Ohi[o] = (U32)h0 | ((U32)h1 << 16);
        *(U32*)&Olo[o] = (U32)l0 | ((U32)l1 << 16);
    }
}

// ---------------- k_mega6: adjT-GEMM (dbuf + swizzle) -> m in LDS -> gates -> GRU ----------------
__global__ __launch_bounds__(256, 2) void k_mega6(
    const U16* __restrict__ adjT,                                 // [NB][NN][NN]
    const U16* __restrict__ hwThi, const U16* __restrict__ hwTlo, // [NB][128][1024]
    const U16* __restrict__ hhi, const U16* __restrict__ hlo,     // [MTOT][128]
    const U16* __restrict__ wihhi, const U16* __restrict__ wihlo, // [384][128] layer slice
    const U16* __restrict__ whhhi, const U16* __restrict__ whhlo,
    const float* __restrict__ bih, const float* __restrict__ bhh, // [384] layer slice
    const float* __restrict__ mask,
    U16* __restrict__ houthi, U16* __restrict__ houtlo,
    float* __restrict__ out, int last)
{
    __shared__ union {
        struct { U16 As[2][64 * 64]; U16 Bh[2][128 * 64]; U16 Bl[2][128 * 64]; } st; // 81920 B
        struct { U16 Mhi[64 * MP]; U16 Mlo[64 * MP]; } m;                            // 34816 B
    } u;
    const int tid = threadIdx.x;
    const int lane = tid & 63, wv = tid >> 6;
    const int wd0 = wv * 32;                       // wave's 32-col slice
    const int lm = lane & 15, lk8 = (lane >> 4) * 8, quad = lane >> 4;
    const int xcd = blockIdx.x & 7;
    const int j = blockIdx.x >> 3;                 // 0..63
    const int bt = xcd * 4 + (j >> 4);
    const int n0 = (j & 15) * 64;
    const int row0 = bt * NN + n0;

    // ---- phase 1: m = adjT @ hw (2-product), dbuf pipeline, XOR-swizzled LDS ----
#define STAGE(kc, b)                                                                     \
    {                                                                                    \
        _Pragma("unroll")                                                                \
        for (int t = 0; t < 2; ++t) {                                                    \
            int li = tid + t * 256; int r = li >> 3, sg = li & 7;                        \
            glds16(&adjT[((size_t)bt << 20) + ((size_t)(n0 + r) << 10) + (kc)            \
                         + ((sg ^ (r & 7)) * 8)],                                        \
                   &u.st.As[b][li * 8]);                                                 \
        }                                                                                \
        _Pragma("unroll")                                                                \
        for (int t = 0; t < 4; ++t) {                                                    \
            int li = tid + t * 256; int d = li >> 3, sg = li & 7;                        \
            size_t o = (((size_t)(bt * 128 + d)) << 10) + (kc) + ((sg ^ (d & 7)) * 8);   \
            glds16(&hwThi[o], &u.st.Bh[b][li * 8]);                                      \
            glds16(&hwTlo[o], &u.st.Bl[b][li * 8]);                                      \
        }                                                                                \
    }

    f32x4 macc[4][2] = {};
    STAGE(0, 0);                                   // prologue
    for (int c = 0; c < 16; ++c) {
        const int b = c & 1;
        __syncthreads();                           // buf b ready
        if (c + 1 < 16) STAGE((c + 1) * 64, b ^ 1);// prefetch, in flight during compute
#pragma unroll
        for (int ks = 0; ks < 2; ++ks) {
            const int g = ks * 4 + quad;           // k-group 0..7
            s16x8 a[4], bh[2], bl[2];
#pragma unroll
            for (int q = 0; q < 4; ++q)
                a[q] = *(const s16x8*)&u.st.As[b][SWZ(q * 16 + lm, g)];
#pragma unroll
            for (int q = 0; q < 2; ++q) {
                bh[q] = *(const s16x8*)&u.st.Bh[b][SWZ(wd0 + q * 16 + lm, g)];
                bl[q] = *(const s16x8*)&u.st.Bl[b][SWZ(wd0 + q * 16 + lm, g)];
            }
#pragma unroll
            for (int rt = 0; rt < 4; ++rt)
#pragma unroll
                for (int ct = 0; ct < 2; ++ct) {
                    f32x4 cc = macc[rt][ct];
                    cc = __builtin_amdgcn_mfma_f32_16x16x32_bf16(a[rt], bh[ct], cc, 0, 0, 0);
                    cc = __builtin_amdgcn_mfma_f32_16x16x32_bf16(a[rt], bl[ct], cc, 0, 0, 0);
                    macc[rt][ct] = cc;
                }
        }
    }
#undef STAGE
    __syncthreads();                               // all waves done reading staging LDS

    // ---- m -> LDS hi/lo (union overwrites staging; bit-identical split values) ----
#pragma unroll
    for (int rt = 0; rt < 4; ++rt)
#pragma unroll
        for (int ct = 0; ct < 2; ++ct)
#pragma unroll
            for (int rr = 0; rr < 4; ++rr) {
                int rloc = rt * 16 + quad * 4 + rr;
                int d = wd0 + ct * 16 + lm;
                U16 hi, lo; splitbf(macc[rt][ct][rr], hi, lo);
                u.m.Mhi[rloc * MP + d] = hi;
                u.m.Mlo[rloc * MP + d] = lo;
            }
    // no barrier yet — h-chunks (no m dependency) run first; barrier before m-chunks

    // ---- phase 2: gates (K=256 concat [m|h], 3-product) + GRU ----
    f32x4 aR[4][2], aZ[4][2], aXN[4][2], aHN[4][2];
#pragma unroll
    for (int ct = 0; ct < 2; ++ct) {
        const int col = wd0 + ct * 16 + lm;
        const float bR  = bih[col]       + bhh[col];
        const float bZ  = bih[128 + col] + bhh[128 + col];
        const float bXN = bih[256 + col];
        const float bHN = bhh[256 + col];
#pragma unroll
        for (int rt = 0; rt < 4; ++rt) {
            aR[rt][ct]  = f32x4{bR, bR, bR, bR};
            aZ[rt][ct]  = f32x4{bZ, bZ, bZ, bZ};
            aXN[rt][ct] = f32x4{bXN, bXN, bXN, bXN};
            aHN[rt][ct] = f32x4{bHN, bHN, bHN, bHN};
        }
    }

    for (int cc = 0; cc < 4; ++cc) {
        const int ch = (cc + 2) & 3;               // order: 2,3 (h, global) then 0,1 (m, LDS)
        if (cc == 2) __syncthreads();              // m ds_writes complete + visible block-wide
        const U16* __restrict__ Whi = (ch < 2) ? wihhi : whhhi;
        const U16* __restrict__ Wlo = (ch < 2) ? wihlo : whhlo;
        const int kb = (ch & 1) * 64;
#pragma unroll
        for (int ks = 0; ks < 2; ++ks) {
            const int ko = kb + ks * 32 + lk8;     // k within [0,128)
            s16x8 ahi[4], alo[4];
            if (ch < 2) {
#pragma unroll
                for (int q = 0; q < 4; ++q) {
                    ahi[q] = *(const s16x8*)&u.m.Mhi[(q * 16 + lm) * MP + ko];
                    alo[q] = *(const s16x8*)&u.m.Mlo[(q * 16 + lm) * MP + ko];
                }
            } else {
#pragma unroll
                for (int q = 0; q < 4; ++q) {
                    size_t ao = (size_t)(row0 + q * 16 + lm) * 128 + ko;
                    ahi[q] = *(const s16x8*)&hhi[ao];
                    alo[q] = *(const s16x8*)&hlo[ao];
                }
            }
#pragma unroll
            for (int ct = 0; ct < 2; ++ct) {
                const int col = wd0 + ct * 16 + lm;
                s16x8 bhiR = *(const s16x8*)&Whi[(size_t)col * 128 + ko];
                s16x8 bloR = *(const s16x8*)&Wlo[(size_t)col * 128 + ko];
                s16x8 bhiZ = *(const s16x8*)&Whi[(size_t)(128 + col) * 128 + ko];
                s16x8 bloZ = *(const s16x8*)&Wlo[(size_t)(128 + col) * 128 + ko];
                s16x8 bhiN = *(const s16x8*)&Whi[(size_t)(256 + col) * 128 + ko];
                s16x8 bloN = *(const s16x8*)&Wlo[(size_t)(256 + col) * 128 + ko];
#pragma unroll
                for (int rt = 0; rt < 4; ++rt) {
                    f32x4 r = aR[rt][ct];
                    r = __builtin_amdgcn_mfma_f32_16x16x32_bf16(ahi[rt], bhiR, r, 0, 0, 0);
                    r = __builtin_amdgcn_mfma_f32_16x16x32_bf16(ahi[rt], bloR, r, 0, 0, 0);
                    r = __builtin_amdgcn_mfma_f32_16x16x32_bf16(alo[rt], bhiR, r, 0, 0, 0);
                    aR[rt][ct] = r;
                    f32x4 z = aZ[rt][ct];
                    z = __builtin_amdgcn_mfma_f32_16x16x32_bf16(ahi[rt], bhiZ, z, 0, 0, 0);
                    z = __builtin_amdgcn_mfma_f32_16x16x32_bf16(ahi[rt], bloZ, z, 0, 0, 0);
                    z = __builtin_amdgcn_mfma_f32_16x16x32_bf16(alo[rt], bhiZ, z, 0, 0, 0);
                    aZ[rt][ct] = z;
                }
                if (ch < 2) {
#pragma unroll
                    for (int rt = 0; rt < 4; ++rt) {
                        f32x4 n = aXN[rt][ct];
                        n = __builtin_amdgcn_mfma_f32_16x16x32_bf16(ahi[rt], bhiN, n, 0, 0, 0);
                        n = __builtin_amdgcn_mfma_f32_16x16x32_bf16(ahi[rt], bloN, n, 0, 0, 0);
                        n = __builtin_amdgcn_mfma_f32_16x16x32_bf16(alo[rt], bhiN, n, 0, 0, 0);
                        aXN[rt][ct] = n;
                    }
                } else {
#pragma unroll
                    for (int rt = 0; rt < 4; ++rt) {
                        f32x4 n = aHN[rt][ct];
                        n = __builtin_amdgcn_mfma_f32_16x16x32_bf16(ahi[rt], bhiN, n, 0, 0, 0);
                        n = __builtin_amdgcn_mfma_f32_16x16x32_bf16(ahi[rt], bloN, n, 0, 0, 0);
                        n = __builtin_amdgcn_mfma_f32_16x16x32_bf16(alo[rt], bhiN, n, 0, 0, 0);
                        aHN[rt][ct] = n;
                    }
                }
            }
        }
    }

    // ---- GRU epilogue; h re-read from global; in-place h update ----
#pragma unroll
    for (int rt = 0; rt < 4; ++rt) {
#pragma unroll
        for (int ct = 0; ct < 2; ++ct) {
            const int col = wd0 + ct * 16 + lm;
#pragma unroll
            for (int rr = 0; rr < 4; ++rr) {
                const int row = row0 + rt * 16 + quad * 4 + rr;
                float r = sigmoidf_(aR[rt][ct][rr]);
                float z = sigmoidf_(aZ[rt][ct][rr]);
                float n = tanhf(aXN[rt][ct][rr] + r * aHN[rt][ct][rr]);
                size_t ho = (size_t)row * 128 + col;
                float hv = bf2f(hhi[ho]) + bf2f(hlo[ho]);
                float hnew = (1.f - z) * n + z * hv;
                if (last) {
                    out[ho] = hnew * mask[row];
                } else {
                    U16 hi2, lo2; splitbf(hnew, hi2, lo2);
                    houthi[ho] = hi2;
                    houtlo[ho] = lo2;
                }
            }
        }
    }
}

// ---------------- launch ----------------
extern "C" void kernel_launch(void* const* d_in, const int* in_sizes, int n_in,
                              void* d_out, int out_size, void* d_ws, size_t ws_size,
                              hipStream_t stream) {
    (void)in_sizes; (void)n_in; (void)out_size; (void)ws_size;
    const float* x    = (const float*)d_in[0];
    const float* adj  = (const float*)d_in[1];
    const float* mask = (const float*)d_in[2];
    const float* wgt  = (const float*)d_in[3];
    const float* wih  = (const float*)d_in[4];
    const float* whh  = (const float*)d_in[5];
    const float* bih  = (const float*)d_in[6];
    const float* bhh  = (const float*)d_in[7];
    float* out = (float*)d_out;

    char* p = (char*)d_ws;
    U16* adjT    = (U16*)p;                p += (size_t)NB * NN * NN * 2;   // 67.1 MB
    U16* h_hi    = (U16*)p;                p += (size_t)MTOT * NC * 2;
    U16* h_lo    = (U16*)p;                p += (size_t)MTOT * NC * 2;
    U16* hwT_hi  = (U16*)p;                p += (size_t)NB * NC * NN * 2;
    U16* hwT_lo  = (U16*)p;                p += (size_t)NB * NC * NN * 2;
    U16* wT_hi   = (U16*)p;                p += (size_t)NL * NC * NC * 2;
    U16* wT_lo   = (U16*)p;                p += (size_t)NL * NC * NC * 2;
    U16* wih_hi  = (U16*)p;                p += (size_t)NL * 384 * NC * 2;
    U16* wih_lo  = (U16*)p;                p += (size_t)NL * 384 * NC * 2;
    U16* whh_hi  = (U16*)p;                p += (size_t)NL * 384 * NC * 2;
    U16* whh_lo  = (U16*)p;                p += (size_t)NL * 384 * NC * 2;

    k_setup<<<12032, 256, 0, stream>>>(adj, adjT, wgt, wih, whh,
                                       wT_hi, wT_lo, wih_hi, wih_lo, whh_hi, whh_lo,
                                       x, h_hi, h_lo);

    for (int l = 0; l < NL; ++l) {
        k_hw<<<256, 256, 0, stream>>>(h_hi, h_lo,
                                      wT_hi + l * 16384, wT_lo + l * 16384,
                                      hwT_hi, hwT_lo);
        k_mega6<<<512, 256, 0, stream>>>(adjT, hwT_hi, hwT_lo, h_hi, h_lo,
                                         wih_hi + l * 49152, wih_lo + l * 49152,
                                         whh_hi + l * 49152, whh_lo + l * 49152,
                                         bih + l * 384, bhh + l * 384, mask,
                                         h_hi, h_lo, out, (l == NL - 1) ? 1 : 0);
    }
}